// Round 1
// baseline (121.866 us; speedup 1.0000x reference)
//
#include <hip/hip_runtime.h>

// Problem constants from the reference (B,T,F fixed; N,M,S derived from sizes).
constexpr int Bc = 2;
constexpr int Tc = 8;
constexpr int Fc = 5;

// One workgroup per (b, t, m). Ordered stream-compaction of the first S points
// inside the cylinder, with early exit. Comparison path uses _rn intrinsics to
// be bit-identical to the f32 numpy/JAX reference (no fma contraction, IEEE sqrt).
__global__ __launch_bounds__(1024) void vox_pool(
    const float* __restrict__ points,        // [B, T, N, F]
    const float* __restrict__ rois,          // [B, T, M, 7]
    const int*   __restrict__ valid_length,  // [B, T, M]
    float*       __restrict__ out,           // [B, M, T, S, F]
    int N, int M, int S)
{
    const int blk = blockIdx.x;
    const int m = blk % M;
    const int t = (blk / M) % Tc;
    const int b = blk / (M * Tc);

    // valid_length==0 && t!=0 -> use frame-0 pooling result: recompute with t_eff=0.
    int t_eff = t;
    if (t != 0 && valid_length[(b * Tc + t) * M + m] == 0) t_eff = 0;

    const float* box = rois + (size_t)((b * Tc + t_eff) * M + m) * 7;
    const float cx = box[0];
    const float cy = box[1];
    const float hl = __fmul_rn(0.5f, box[3]);
    const float hw = __fmul_rn(0.5f, box[4]);
    // radii = norm([l,w]*0.5) * 1.1 in f32, rounded per-op like the reference
    const float r = __fmul_rn(__fsqrt_rn(__fadd_rn(__fmul_rn(hl, hl), __fmul_rn(hw, hw))), 1.1f);

    const float* pts = points + (size_t)(b * Tc + t_eff) * N * Fc;
    float* o = out + ((size_t)(b * M + m) * Tc + t) * (size_t)S * Fc;

    __shared__ int wcnt[16];

    const int tid  = threadIdx.x;
    const int lane = tid & 63;
    const int wav  = tid >> 6;
    const int nthreads = blockDim.x;
    const int nwaves = nthreads >> 6;

    int cnt = 0;  // number of inside-points seen so far (uniform across block)
    for (int base = 0; base < N; base += nthreads) {
        const int idx = base + tid;
        bool inside = false;
        if (idx < N) {
            const float px = pts[(size_t)idx * Fc + 0];
            const float py = pts[(size_t)idx * Fc + 1];
            const float dx = __fsub_rn(px, cx);
            const float dy = __fsub_rn(py, cy);
            const float d2 = __fadd_rn(__fmul_rn(dx, dx), __fmul_rn(dy, dy));
            inside = (__fsqrt_rn(d2) <= r);
        }
        const unsigned long long bal = __ballot(inside);
        if (lane == 0) wcnt[wav] = __popcll(bal);
        __syncthreads();

        int wave_off = 0, block_tot = 0;
        #pragma unroll
        for (int w = 0; w < 16; ++w) {
            if (w < nwaves) {
                const int c = wcnt[w];
                if (w < wav) wave_off += c;
                block_tot += c;
            }
        }

        if (inside) {
            const int slot = cnt + wave_off + __popcll(bal & ((1ull << lane) - 1ull));
            if (slot < S) {
                #pragma unroll
                for (int f = 0; f < Fc; ++f)
                    o[(size_t)slot * Fc + f] = pts[(size_t)idx * Fc + f];
            }
        }
        cnt += block_tot;
        __syncthreads();  // protect wcnt reuse next iteration
        if (cnt >= S) break;
    }

    // Zero the tail slots [min(cnt,S), S)
    const int filled = cnt < S ? cnt : S;
    for (int s = filled + tid; s < S; s += nthreads) {
        #pragma unroll
        for (int f = 0; f < Fc; ++f)
            o[(size_t)s * Fc + f] = 0.0f;
    }
}

extern "C" void kernel_launch(void* const* d_in, const int* in_sizes, int n_in,
                              void* d_out, int out_size, void* d_ws, size_t ws_size,
                              hipStream_t stream) {
    const float* points = (const float*)d_in[0];
    const float* rois   = (const float*)d_in[1];
    const int*   vlen   = (const int*)d_in[2];
    float* out = (float*)d_out;

    const int N = in_sizes[0] / (Bc * Tc * Fc);   // 65536
    const int M = in_sizes[2] / (Bc * Tc);        // 128
    const int S = out_size / (Bc * M * Tc * Fc);  // 128 (num_sample)

    dim3 grid(Bc * Tc * M);
    vox_pool<<<grid, 1024, 0, stream>>>(points, rois, vlen, out, N, M, S);
}

// Round 2
// 79.913 us; speedup vs baseline: 1.5250x; 1.5250x over previous
//
#include <hip/hip_runtime.h>

// Problem constants from the reference (B,T,F fixed; N,M,S derived from sizes).
constexpr int Bc  = 2;
constexpr int Tc  = 8;
constexpr int Fc  = 5;
constexpr int NT  = 1024;        // threads per block
constexpr int PPT = 4;           // points per thread per chunk (4 pts = 5 float4s)
constexpr int CHUNK = NT * PPT;  // 4096 points per iteration

// One workgroup per (b, t, m). Ordered stream-compaction of the first S points
// inside the cylinder, early exit. Per iteration: coalesced float4 loads of 4
// points/thread (payload kept in regs for the winners' store), 4 ballots for an
// ordered intra-wave prefix, ONE barrier via parity-double-buffered wave counts,
// and a prefetch of the next chunk issued before the barrier.
// Comparison path uses _rn intrinsics for bit-identical f32 vs the numpy ref.
__global__ __launch_bounds__(1024) void vox_pool(
    const float* __restrict__ points,        // [B, T, N, F]
    const float* __restrict__ rois,          // [B, T, M, 7]
    const int*   __restrict__ valid_length,  // [B, T, M]
    float*       __restrict__ out,           // [B, M, T, S, F]
    int N, int M, int S)
{
    const int blk = blockIdx.x;
    const int m = blk % M;
    const int t = (blk / M) % Tc;
    const int b = blk / (M * Tc);

    // valid_length==0 && t!=0 -> frame-0 result: recompute with t_eff=0.
    int t_eff = t;
    if (t != 0 && valid_length[(b * Tc + t) * M + m] == 0) t_eff = 0;

    const float* box = rois + (size_t)((b * Tc + t_eff) * M + m) * 7;
    const float cx = box[0];
    const float cy = box[1];
    const float hl = __fmul_rn(0.5f, box[3]);
    const float hw = __fmul_rn(0.5f, box[4]);
    const float r  = __fmul_rn(__fsqrt_rn(__fadd_rn(__fmul_rn(hl, hl), __fmul_rn(hw, hw))), 1.1f);

    const float* pts = points + (size_t)(b * Tc + t_eff) * N * Fc;
    float* o = out + ((size_t)(b * M + m) * Tc + t) * (size_t)S * Fc;

    __shared__ int wcnt[2][16];

    const int tid  = threadIdx.x;
    const int lane = tid & 63;
    const int wav  = tid >> 6;
    const unsigned long long lt = (1ull << lane) - 1ull;

    const int niter = (N + CHUNK - 1) / CHUNK;
    // Per-thread chunk start (clamped so the 5 float4 loads stay in bounds and
    // 16B-aligned; requires N % 4 == 0, true here).
    auto chunk_base = [&](int it_) {
        int p = it_ * CHUNK + tid * PPT;
        return p <= N - PPT ? p : N - PPT;
    };

    float4 buf[5];
    {
        const float4* src = (const float4*)(pts + (size_t)chunk_base(0) * Fc);
        #pragma unroll
        for (int q = 0; q < 5; ++q) buf[q] = src[q];
    }

    int cnt = 0;     // inside-points seen so far (uniform across block)
    int parity = 0;

    for (int it = 0; it < niter; ++it) {
        // ---- prefetch next chunk (overlaps with mask/ballot below) ----
        float4 nbuf[5];
        if (it + 1 < niter) {
            const float4* src = (const float4*)(pts + (size_t)chunk_base(it + 1) * Fc);
            #pragma unroll
            for (int q = 0; q < 5; ++q) nbuf[q] = src[q];
        }

        // ---- test own 4 points, build ordered intra-wave prefix ----
        const float* f = (const float*)buf;  // 20 floats = 4 consecutive points
        unsigned msk = 0;
        int lanepre = 0, wtot = 0;
        #pragma unroll
        for (int k = 0; k < PPT; ++k) {
            const int idx = it * CHUNK + tid * PPT + k;
            const float dx = __fsub_rn(f[5 * k + 0], cx);
            const float dy = __fsub_rn(f[5 * k + 1], cy);
            const float d2 = __fadd_rn(__fmul_rn(dx, dx), __fmul_rn(dy, dy));
            const bool inside = (__fsqrt_rn(d2) <= r) && (idx < N);
            const unsigned long long bk = __ballot(inside);
            if (inside) msk |= (1u << k);
            lanepre += (int)__popcll(bk & lt);
            wtot    += (int)__popcll(bk);
        }
        if (lane == 0) wcnt[parity][wav] = wtot;

        __syncthreads();  // the single barrier per iteration

        int wave_off = 0, block_tot = 0;
        #pragma unroll
        for (int w = 0; w < 16; ++w) {
            const int c = wcnt[parity][w];
            if (w < wav) wave_off += c;
            block_tot += c;
        }

        // ---- winners write their payload straight from registers ----
        if (msk) {
            const int sbase = cnt + wave_off + lanepre;
            #pragma unroll
            for (int k = 0; k < PPT; ++k) {
                if (msk & (1u << k)) {
                    const int slot = sbase + __popc(msk & ((1u << k) - 1u));
                    if (slot < S) {
                        #pragma unroll
                        for (int q = 0; q < Fc; ++q)
                            o[(size_t)slot * Fc + q] = f[5 * k + q];
                    }
                }
            }
        }

        cnt += block_tot;
        parity ^= 1;
        if (cnt >= S) break;

        #pragma unroll
        for (int q = 0; q < 5; ++q) buf[q] = nbuf[q];
    }

    // Zero the tail slots [min(cnt,S), S)
    const int filled = cnt < S ? cnt : S;
    for (int s = filled + tid; s < S; s += NT) {
        #pragma unroll
        for (int q = 0; q < Fc; ++q)
            o[(size_t)s * Fc + q] = 0.0f;
    }
}

extern "C" void kernel_launch(void* const* d_in, const int* in_sizes, int n_in,
                              void* d_out, int out_size, void* d_ws, size_t ws_size,
                              hipStream_t stream) {
    const float* points = (const float*)d_in[0];
    const float* rois   = (const float*)d_in[1];
    const int*   vlen   = (const int*)d_in[2];
    float* out = (float*)d_out;

    const int N = in_sizes[0] / (Bc * Tc * Fc);   // 65536
    const int M = in_sizes[2] / (Bc * Tc);        // 128
    const int S = out_size / (Bc * M * Tc * Fc);  // 128 (num_sample)

    dim3 grid(Bc * Tc * M);
    vox_pool<<<grid, NT, 0, stream>>>(points, rois, vlen, out, N, M, S);
}